// Round 2
// baseline (8853.448 us; speedup 1.0000x reference)
//
#include <hip/hip_runtime.h>

// SNN: 4 LIF layers, T=25, B=256. All GEMM accumulation + LIF recursion in
// fp64 so the computed trajectory is ~exact; binary spike outputs then match
// any correctly-rounded reference. fp64 membrane state carried in d_ws
// (written at t=0 before ever being read -> poison-safe, deterministic).
//
// d_out (fp32) layout, reference return order, each [T,B,feat]:
//   s1,s2,s3 [25,256,2048], s4 [25,256,10],
//   m1..m3, m4, c1..c3, c4 (same shapes)
// d_out doubles as intermediate storage: spk_l[t] feeds layer l+1.

#define BM 32
#define BN 64
#define BK 32

__global__ __launch_bounds__(256)
void gemm_lif_f64(const float* __restrict__ A, int lda,
                  const float* __restrict__ W,
                  const float* __restrict__ bias,
                  const double* __restrict__ m64_in,   // fp64 mem carry (null at t==0 / no ws)
                  const float* __restrict__ m32_in,    // fp32 fallback (null at t==0)
                  double* __restrict__ m64_out,        // may be null
                  float* __restrict__ cur_out,
                  float* __restrict__ mem_out,
                  float* __restrict__ spk_out,
                  const float* __restrict__ beta_p,
                  const float* __restrict__ thr_p,
                  int K, int N)
{
    __shared__ double As[BK][BM + 4];   // row stride 36 doubles -> 16B-aligned rows
    __shared__ double Ws[BK][BN + 4];   // row stride 68 doubles

    const int tid = threadIdx.x;
    const int bm = blockIdx.y * BM;
    const int bn = blockIdx.x * BN;

    const int tx = tid & 15;   // n-dim
    const int ty = tid >> 4;   // m-dim
    const int n0 = tx * 4;
    const int m0 = ty * 2;

    const int arow = tid >> 3;        // 0..31
    const int acol = (tid & 7) * 4;   // 0,4,...,28

    double acc[2][4] = {{0.0,0.0,0.0,0.0},{0.0,0.0,0.0,0.0}};

    for (int kt = 0; kt < K; kt += BK) {
        float4 av = *reinterpret_cast<const float4*>(A + (size_t)(bm + arow) * lda + kt + acol);
        As[acol + 0][arow] = (double)av.x;
        As[acol + 1][arow] = (double)av.y;
        As[acol + 2][arow] = (double)av.z;
        As[acol + 3][arow] = (double)av.w;
#pragma unroll
        for (int r = 0; r < 2; ++r) {
            int n = arow + r * 32;
            float4 wv = *reinterpret_cast<const float4*>(W + (size_t)(bn + n) * K + kt + acol);
            Ws[acol + 0][n] = (double)wv.x;
            Ws[acol + 1][n] = (double)wv.y;
            Ws[acol + 2][n] = (double)wv.z;
            Ws[acol + 3][n] = (double)wv.w;
        }
        __syncthreads();
#pragma unroll
        for (int k = 0; k < BK; ++k) {
            double2 a  = *reinterpret_cast<const double2*>(&As[k][m0]);
            double2 w0 = *reinterpret_cast<const double2*>(&Ws[k][n0]);
            double2 w1 = *reinterpret_cast<const double2*>(&Ws[k][n0 + 2]);
            acc[0][0] += a.x * w0.x; acc[0][1] += a.x * w0.y;
            acc[0][2] += a.x * w1.x; acc[0][3] += a.x * w1.y;
            acc[1][0] += a.y * w0.x; acc[1][1] += a.y * w0.y;
            acc[1][2] += a.y * w1.x; acc[1][3] += a.y * w1.y;
        }
        __syncthreads();
    }

    const double beta = fmin(fmax((double)*beta_p, 0.0), 1.0);
    const double thr  = (double)*thr_p;

#pragma unroll
    for (int r = 0; r < 2; ++r) {
        const int i = bm + m0 + r;
        const size_t off = (size_t)i * N + bn + n0;
        float4 cf, mf, sf;
        float* cfp = &cf.x; float* mfp = &mf.x; float* sfp = &sf.x;
#pragma unroll
        for (int j = 0; j < 4; ++j) {
            double cur = acc[r][j] + (double)bias[bn + n0 + j];
            double mp;
            if (m64_in)      mp = m64_in[off + j];
            else if (m32_in) mp = (double)m32_in[off + j];
            else             mp = 0.0;
            double reset = (mp > thr) ? 1.0 : 0.0;
            double mem = beta * mp + cur - reset * thr;
            cfp[j] = (float)cur;
            mfp[j] = (float)mem;
            sfp[j] = (mem > thr) ? 1.0f : 0.0f;
            if (m64_out) m64_out[off + j] = mem;
        }
        *reinterpret_cast<float4*>(cur_out + off) = cf;
        *reinterpret_cast<float4*>(mem_out + off) = mf;
        *reinterpret_cast<float4*>(spk_out + off) = sf;
    }
}

// Layer 4: [256,10] = spk3 @ W4^T + b4, fp64 accumulate, fused LIF.
__global__ __launch_bounds__(256)
void fc4_lif_f64(const float* __restrict__ A,
                 const float* __restrict__ W,
                 const float* __restrict__ bias,
                 const double* __restrict__ m64_in,
                 const float* __restrict__ m32_in,
                 double* __restrict__ m64_out,
                 float* __restrict__ cur_out,
                 float* __restrict__ mem_out,
                 float* __restrict__ spk_out,
                 const float* __restrict__ beta_p,
                 const float* __restrict__ thr_p)
{
    const int wave = threadIdx.x >> 6;
    const int lane = threadIdx.x & 63;
    const int i = blockIdx.x * 4 + wave;

    float a[32];
#pragma unroll
    for (int m = 0; m < 32; ++m)
        a[m] = A[(size_t)i * 2048 + lane + 64 * m];

    const double beta = fmin(fmax((double)*beta_p, 0.0), 1.0);
    const double thr  = (double)*thr_p;

    for (int j = 0; j < 10; ++j) {
        double s = 0.0;
#pragma unroll
        for (int m = 0; m < 32; ++m)
            s += (double)a[m] * (double)W[(size_t)j * 2048 + lane + 64 * m];
#pragma unroll
        for (int o = 32; o > 0; o >>= 1)
            s += __shfl_down(s, o);
        if (lane == 0) {
            double cur = s + (double)bias[j];
            double mp;
            if (m64_in)      mp = m64_in[i * 10 + j];
            else if (m32_in) mp = (double)m32_in[i * 10 + j];
            else             mp = 0.0;
            double reset = (mp > thr) ? 1.0 : 0.0;
            double mem = beta * mp + cur - reset * thr;
            cur_out[i * 10 + j] = (float)cur;
            mem_out[i * 10 + j] = (float)mem;
            spk_out[i * 10 + j] = (mem > thr) ? 1.0f : 0.0f;
            if (m64_out) m64_out[i * 10 + j] = mem;
        }
    }
}

extern "C" void kernel_launch(void* const* d_in, const int* in_sizes, int n_in,
                              void* d_out, int out_size, void* d_ws, size_t ws_size,
                              hipStream_t stream) {
    const float* x  = (const float*)d_in[0];
    const float* W1 = (const float*)d_in[1];
    const float* b1 = (const float*)d_in[2];
    const float* W2 = (const float*)d_in[3];
    const float* b2 = (const float*)d_in[4];
    const float* W3 = (const float*)d_in[5];
    const float* b3 = (const float*)d_in[6];
    const float* W4 = (const float*)d_in[7];
    const float* b4 = (const float*)d_in[8];
    const float* beta1 = (const float*)d_in[9];
    const float* beta2 = (const float*)d_in[10];
    const float* beta3 = (const float*)d_in[11];
    const float* beta4 = (const float*)d_in[12];
    const float* thr1 = (const float*)d_in[13];
    const float* thr2 = (const float*)d_in[14];
    const float* thr3 = (const float*)d_in[15];
    const float* thr4 = (const float*)d_in[16];

    float* out = (float*)d_out;
    const size_t SB  = 25L * 256 * 2048;
    const size_t SB4 = 25L * 256 * 10;
    float* s1 = out;
    float* s2 = out + SB;
    float* s3 = out + 2 * SB;
    float* s4 = out + 3 * SB;
    float* m1 = s4 + SB4;
    float* m2 = m1 + SB;
    float* m3 = m1 + 2 * SB;
    float* m4 = m1 + 3 * SB;
    float* c1 = m4 + SB4;
    float* c2 = c1 + SB;
    float* c3 = c1 + 2 * SB;
    float* c4 = c1 + 3 * SB;

    // fp64 membrane carry in workspace (if it fits)
    const size_t NL = 256 * 2048;          // per-layer state elems (big layers)
    const size_t WS_NEED = (3 * NL + 256 * 10) * sizeof(double);
    const bool use64 = (d_ws != nullptr) && (ws_size >= WS_NEED);
    double* wsd = (double*)d_ws;
    double* mm1 = use64 ? wsd          : nullptr;
    double* mm2 = use64 ? wsd + NL     : nullptr;
    double* mm3 = use64 ? wsd + 2 * NL : nullptr;
    double* mm4 = use64 ? wsd + 3 * NL : nullptr;

    const dim3 grid(2048 / BN, 256 / BM);  // (32, 8)
    const int PT  = 256 * 2048;
    const int PT4 = 256 * 10;

    for (int t = 0; t < 25; ++t) {
        const size_t po  = (size_t)t * PT;
        const size_t po4 = (size_t)t * PT4;

        gemm_lif_f64<<<grid, 256, 0, stream>>>(
            x + (size_t)t * 768, 25 * 768, W1, b1,
            t ? mm1 : nullptr, t ? m1 + po - PT : nullptr, mm1,
            c1 + po, m1 + po, s1 + po, beta1, thr1, 768, 2048);

        gemm_lif_f64<<<grid, 256, 0, stream>>>(
            s1 + po, 2048, W2, b2,
            t ? mm2 : nullptr, t ? m2 + po - PT : nullptr, mm2,
            c2 + po, m2 + po, s2 + po, beta2, thr2, 2048, 2048);

        gemm_lif_f64<<<grid, 256, 0, stream>>>(
            s2 + po, 2048, W3, b3,
            t ? mm3 : nullptr, t ? m3 + po - PT : nullptr, mm3,
            c3 + po, m3 + po, s3 + po, beta3, thr3, 2048, 2048);

        fc4_lif_f64<<<64, 256, 0, stream>>>(
            s3 + po, W4, b4,
            t ? mm4 : nullptr, t ? m4 + po4 - PT4 : nullptr, mm4,
            c4 + po4, m4 + po4, s4 + po4, beta4, thr4);
    }
}

// Round 3
// 2399.880 us; speedup vs baseline: 3.6891x; 3.6891x over previous
//
#include <hip/hip_runtime.h>

// SNN 4-layer LIF, T=25, B=256, exact-integer MFMA path.
// Accuracy strategy: all GEMM arithmetic is EXACT integer (i8 MFMA digit
// planes, i32 accumulate, fp64 reconstruction) + fp64 LIF recursion =>
// trajectory matches an fp64 reference to ~1e-10, far inside spike margins.
//
// d_out (fp32) layout (reference return order), each [T,B,feat]:
//   s1,s2,s3 [25,256,2048], s4 [25,256,10], m1..m4, c1..c4 (same shapes)

typedef int v4i  __attribute__((ext_vector_type(4)));
typedef int v16i __attribute__((ext_vector_type(16)));

#define T_   25
#define BB   256
#define DIN  768
#define HH   2048
#define PT   (BB*HH)      // 524288 per-timestep elems (big layers)
#define PT4  (BB*10)

// ---------------- digit decompose kernels ----------------
// balanced base-256 digits: V = sum d_p * 256^p, d_p in [-128,127]

// x[B][T][DIN] -> 5 planes, scale 2^35, MFMA-A-fragment-swizzled:
// layout [rtile(200)][kc(24)][plane(5)][lane(64)][16B], lane=(khalf*32)|(row&31)
__global__ __launch_bounds__(256)
void k_decomp_x(const float* __restrict__ x, char* __restrict__ xpl)
{
    int gid = blockIdx.x * 256 + threadIdx.x;      // 6400*48
    int r = gid / 48, rem = gid % 48;
    int kc = rem >> 1, h = rem & 1;
    int t = r >> 8, b = r & 255;
    const float* src = x + ((size_t)b * T_ + t) * DIN + kc * 32 + h * 16;
    alignas(16) char dig[5][16];
#pragma unroll
    for (int e = 0; e < 16; ++e) {
        long long V = llround((double)src[e] * 34359738368.0);  // 2^35
#pragma unroll
        for (int p = 0; p < 4; ++p) {
            int d = (int)(V & 255); if (d >= 128) d -= 256;
            dig[p][e] = (char)d; V = (V - d) >> 8;
        }
        dig[4][e] = (char)V;
    }
    size_t base = (((size_t)(r >> 5) * 24 + kc) * 5) * 1024 + (size_t)(h * 32 + (r & 31)) * 16;
#pragma unroll
    for (int p = 0; p < 5; ++p)
        *(int4*)(xpl + base + (size_t)p * 1024) = *(const int4*)dig[p];
}

// W[N=2048][K] -> NDIG planes, scale 2^QSH, MFMA-B-fragment-swizzled:
// layout [ntile][kc(KC)][plane(NDIG)][lane][16B], lane=(khalf*32)|(n&31)
template<int NDIG, int QSH, int KC>
__global__ __launch_bounds__(256)
void k_decomp_w(const float* __restrict__ W, char* __restrict__ wpl, int K)
{
    int gid = blockIdx.x * 256 + threadIdx.x;      // 2048*KC*2
    int n = gid / (KC * 2), rem = gid % (KC * 2);
    int kc = rem >> 1, h = rem & 1;
    const float* src = W + (size_t)n * K + kc * 32 + h * 16;
    const double scale = (double)(1ULL << QSH);
    alignas(16) char dig[NDIG][16];
#pragma unroll
    for (int e = 0; e < 16; ++e) {
        long long V = llround((double)src[e] * scale);
#pragma unroll
        for (int p = 0; p < NDIG - 1; ++p) {
            int d = (int)(V & 255); if (d >= 128) d -= 256;
            dig[p][e] = (char)d; V = (V - d) >> 8;
        }
        dig[NDIG - 1][e] = (char)V;
    }
    size_t base = (((size_t)(n >> 5) * KC + kc) * NDIG) * 1024 + (size_t)(h * 32 + (n & 31)) * 16;
#pragma unroll
    for (int p = 0; p < NDIG; ++p)
        *(int4*)(wpl + base + (size_t)p * 1024) = *(const int4*)dig[p];
}

// ---------------- layer-1 big GEMM: c1[6400][2048] = x @ W1^T + b1 ----------------
// x 5 digits (2^35) x W1 5 digits (2^42); keep pairs with s=i+j>=4, bank=s-4.
__global__ __launch_bounds__(256)
void k_gemm1(const char* __restrict__ xpl, const char* __restrict__ w1pl,
             const float* __restrict__ b1, float* __restrict__ c1)
{
    int wid = threadIdx.x >> 6, l = threadIdx.x & 63;
    int mt = blockIdx.y * 4 + wid;     // 0..199
    int nt = blockIdx.x;               // 0..63
    v16i acc[5] = {};
    const char* ab = xpl  + ((size_t)mt * 24) * 5 * 1024 + (size_t)l * 16;
    const char* wb = w1pl + ((size_t)nt * 24) * 5 * 1024 + (size_t)l * 16;
    for (int kc = 0; kc < 24; ++kc) {
        v4i a[5], w[5];
#pragma unroll
        for (int p = 0; p < 5; ++p) {
            a[p] = *(const v4i*)(ab + (size_t)(kc * 5 + p) * 1024);
            w[p] = *(const v4i*)(wb + (size_t)(kc * 5 + p) * 1024);
        }
        acc[0] = __builtin_amdgcn_mfma_i32_32x32x32_i8(a[0], w[4], acc[0], 0, 0, 0);
        acc[0] = __builtin_amdgcn_mfma_i32_32x32x32_i8(a[1], w[3], acc[0], 0, 0, 0);
        acc[0] = __builtin_amdgcn_mfma_i32_32x32x32_i8(a[2], w[2], acc[0], 0, 0, 0);
        acc[0] = __builtin_amdgcn_mfma_i32_32x32x32_i8(a[3], w[1], acc[0], 0, 0, 0);
        acc[0] = __builtin_amdgcn_mfma_i32_32x32x32_i8(a[4], w[0], acc[0], 0, 0, 0);
        acc[1] = __builtin_amdgcn_mfma_i32_32x32x32_i8(a[1], w[4], acc[1], 0, 0, 0);
        acc[1] = __builtin_amdgcn_mfma_i32_32x32x32_i8(a[2], w[3], acc[1], 0, 0, 0);
        acc[1] = __builtin_amdgcn_mfma_i32_32x32x32_i8(a[3], w[2], acc[1], 0, 0, 0);
        acc[1] = __builtin_amdgcn_mfma_i32_32x32x32_i8(a[4], w[1], acc[1], 0, 0, 0);
        acc[2] = __builtin_amdgcn_mfma_i32_32x32x32_i8(a[2], w[4], acc[2], 0, 0, 0);
        acc[2] = __builtin_amdgcn_mfma_i32_32x32x32_i8(a[3], w[3], acc[2], 0, 0, 0);
        acc[2] = __builtin_amdgcn_mfma_i32_32x32x32_i8(a[4], w[2], acc[2], 0, 0, 0);
        acc[3] = __builtin_amdgcn_mfma_i32_32x32x32_i8(a[3], w[4], acc[3], 0, 0, 0);
        acc[3] = __builtin_amdgcn_mfma_i32_32x32x32_i8(a[4], w[3], acc[3], 0, 0, 0);
        acc[4] = __builtin_amdgcn_mfma_i32_32x32x32_i8(a[4], w[4], acc[4], 0, 0, 0);
    }
    int half = l >> 5, lr = l & 31;
    int col = nt * 32 + lr;
    double bias = (double)b1[col];
#pragma unroll
    for (int e = 0; e < 16; ++e) {
        int row = (e & 3) + 8 * (e >> 2) + 4 * half;
        int r = mt * 32 + row;
        double hi = (((double)acc[4][e] * 256.0 + (double)acc[3][e]) * 256.0 + (double)acc[2][e]);
        double lo = ((double)acc[1][e] * 256.0 + (double)acc[0][e]);
        // scale: 256^6*2^-77 = 2^-29 ; 256^4*2^-77 = 2^-45
        double v = hi * 1.862645149230957e-09 + lo * 2.842170943040401e-14 + bias;
        c1[(size_t)r * HH + col] = (float)v;
    }
}

// ---------------- LIF scan for layer 1 (all 25 steps, elementwise) ----------------
__global__ __launch_bounds__(256)
void k_lif1(const float* __restrict__ c1, float* __restrict__ m1, float* __restrict__ s1,
            char* __restrict__ s1q, const float* __restrict__ beta_p, const float* __restrict__ thr_p)
{
    int idx = blockIdx.x * 256 + threadIdx.x;   // 524288
    double beta = fmin(fmax((double)*beta_p, 0.0), 1.0);
    double thr  = (double)*thr_p;
    double mem = 0.0;
    for (int t = 0; t < T_; ++t) {
        size_t off = (size_t)t * PT + idx;
        double cur = (double)c1[off];
        double reset = (mem > thr) ? 1.0 : 0.0;
        mem = beta * mem + cur - reset * thr;
        float spk = (mem > thr) ? 1.f : 0.f;
        m1[off] = (float)mem; s1[off] = spk; s1q[off] = (char)(spk != 0.f);
    }
}

// ---------------- layers 2/3: spikes(i8 0/1) x W 4-digit planes + fused LIF ----------------
__global__ __launch_bounds__(64)
void k_gemm23(const char* __restrict__ aq, const char* __restrict__ wpl,
              const float* __restrict__ bias, double* __restrict__ mws,
              float* __restrict__ cur_o, float* __restrict__ mem_o, float* __restrict__ spk_o,
              char* __restrict__ sq_out,
              const float* __restrict__ beta_p, const float* __restrict__ thr_p, int t0)
{
    int l = threadIdx.x, half = l >> 5, lr = l & 31;
    int nt = blockIdx.x, mt = blockIdx.y;
    v16i acc[4] = {};
    const char* ab = aq + (size_t)(mt * 32 + lr) * HH + half * 16;
    const char* wb = wpl + ((size_t)nt * 64) * 4 * 1024 + (size_t)l * 16;
#pragma unroll 4
    for (int kc = 0; kc < 64; ++kc) {
        v4i a = *(const v4i*)(ab + (size_t)kc * 32);
        v4i w0 = *(const v4i*)(wb + (size_t)(kc * 4 + 0) * 1024);
        v4i w1 = *(const v4i*)(wb + (size_t)(kc * 4 + 1) * 1024);
        v4i w2 = *(const v4i*)(wb + (size_t)(kc * 4 + 2) * 1024);
        v4i w3 = *(const v4i*)(wb + (size_t)(kc * 4 + 3) * 1024);
        acc[0] = __builtin_amdgcn_mfma_i32_32x32x32_i8(a, w0, acc[0], 0, 0, 0);
        acc[1] = __builtin_amdgcn_mfma_i32_32x32x32_i8(a, w1, acc[1], 0, 0, 0);
        acc[2] = __builtin_amdgcn_mfma_i32_32x32x32_i8(a, w2, acc[2], 0, 0, 0);
        acc[3] = __builtin_amdgcn_mfma_i32_32x32x32_i8(a, w3, acc[3], 0, 0, 0);
    }
    double beta = fmin(fmax((double)*beta_p, 0.0), 1.0);
    double thr  = (double)*thr_p;
    int col = nt * 32 + lr;
    double bv = (double)bias[col];
#pragma unroll
    for (int e = 0; e < 16; ++e) {
        int row = (e & 3) + 8 * (e >> 2) + 4 * half;
        size_t off = (size_t)(mt * 32 + row) * HH + col;
        double dot = ((((double)acc[3][e] * 256.0 + (double)acc[2][e]) * 256.0
                       + (double)acc[1][e]) * 256.0 + (double)acc[0][e]) * 2.9103830456733704e-11; // 2^-35
        double cur = dot + bv;
        double mp = t0 ? 0.0 : mws[off];
        double reset = (mp > thr) ? 1.0 : 0.0;
        double mem = beta * mp + cur - reset * thr;
        float spk = (mem > thr) ? 1.f : 0.f;
        cur_o[off] = (float)cur; mem_o[off] = (float)mem; spk_o[off] = spk;
        mws[off] = mem;
        if (sq_out) sq_out[off] = (char)(spk != 0.f);
    }
}

// ---------------- layer 4: fp64 wave-dot ----------------
__global__ __launch_bounds__(256)
void k_fc4(const float* __restrict__ A, const float* __restrict__ W,
           const float* __restrict__ bias, double* __restrict__ m4ws,
           float* __restrict__ c4, float* __restrict__ m4, float* __restrict__ s4,
           const float* __restrict__ beta_p, const float* __restrict__ thr_p, int t0)
{
    int wid = threadIdx.x >> 6, lane = threadIdx.x & 63;
    int i = blockIdx.x * 4 + wid;
    double a[32];
#pragma unroll
    for (int m = 0; m < 32; ++m)
        a[m] = (double)A[(size_t)i * HH + lane + 64 * m];
    double beta = fmin(fmax((double)*beta_p, 0.0), 1.0);
    double thr  = (double)*thr_p;
    for (int j = 0; j < 10; ++j) {
        double s = 0.0;
#pragma unroll
        for (int m = 0; m < 32; ++m)
            s += a[m] * (double)W[(size_t)j * HH + lane + 64 * m];
#pragma unroll
        for (int o = 32; o > 0; o >>= 1)
            s += __shfl_down(s, o);
        if (lane == 0) {
            double cur = s + (double)bias[j];
            double mp = t0 ? 0.0 : m4ws[i * 10 + j];
            double reset = (mp > thr) ? 1.0 : 0.0;
            double mem = beta * mp + cur - reset * thr;
            c4[i * 10 + j] = (float)cur; m4[i * 10 + j] = (float)mem;
            s4[i * 10 + j] = (mem > thr) ? 1.f : 0.f;
            m4ws[i * 10 + j] = mem;
        }
    }
}

// ---------------- fp64 fallback (round-2, known-good) ----------------
#define BM 32
#define BN 64
#define BK 32
__global__ __launch_bounds__(256)
void gemm_lif_f64(const float* __restrict__ A, int lda, const float* __restrict__ W,
                  const float* __restrict__ bias, const double* __restrict__ m64_in,
                  const float* __restrict__ m32_in, double* __restrict__ m64_out,
                  float* __restrict__ cur_out, float* __restrict__ mem_out, float* __restrict__ spk_out,
                  const float* __restrict__ beta_p, const float* __restrict__ thr_p, int K, int N)
{
    __shared__ double As[BK][BM + 4];
    __shared__ double Ws[BK][BN + 4];
    const int tid = threadIdx.x;
    const int bm = blockIdx.y * BM, bn = blockIdx.x * BN;
    const int tx = tid & 15, ty = tid >> 4;
    const int n0 = tx * 4, m0 = ty * 2;
    const int arow = tid >> 3, acol = (tid & 7) * 4;
    double acc[2][4] = {{0,0,0,0},{0,0,0,0}};
    for (int kt = 0; kt < K; kt += BK) {
        float4 av = *reinterpret_cast<const float4*>(A + (size_t)(bm + arow) * lda + kt + acol);
        As[acol+0][arow]=av.x; As[acol+1][arow]=av.y; As[acol+2][arow]=av.z; As[acol+3][arow]=av.w;
#pragma unroll
        for (int r = 0; r < 2; ++r) {
            int n = arow + r * 32;
            float4 wv = *reinterpret_cast<const float4*>(W + (size_t)(bn + n) * K + kt + acol);
            Ws[acol+0][n]=wv.x; Ws[acol+1][n]=wv.y; Ws[acol+2][n]=wv.z; Ws[acol+3][n]=wv.w;
        }
        __syncthreads();
#pragma unroll
        for (int k = 0; k < BK; ++k) {
            double2 a  = *reinterpret_cast<const double2*>(&As[k][m0]);
            double2 w0 = *reinterpret_cast<const double2*>(&Ws[k][n0]);
            double2 w1 = *reinterpret_cast<const double2*>(&Ws[k][n0 + 2]);
            acc[0][0]+=a.x*w0.x; acc[0][1]+=a.x*w0.y; acc[0][2]+=a.x*w1.x; acc[0][3]+=a.x*w1.y;
            acc[1][0]+=a.y*w0.x; acc[1][1]+=a.y*w0.y; acc[1][2]+=a.y*w1.x; acc[1][3]+=a.y*w1.y;
        }
        __syncthreads();
    }
    const double beta = fmin(fmax((double)*beta_p, 0.0), 1.0);
    const double thr  = (double)*thr_p;
#pragma unroll
    for (int r = 0; r < 2; ++r) {
        const size_t off = (size_t)(bm + m0 + r) * N + bn + n0;
        float4 cf, mf, sf;
        float* cfp=&cf.x; float* mfp=&mf.x; float* sfp=&sf.x;
#pragma unroll
        for (int j = 0; j < 4; ++j) {
            double cur = acc[r][j] + (double)bias[bn + n0 + j];
            double mp = m64_in ? m64_in[off + j] : (m32_in ? (double)m32_in[off + j] : 0.0);
            double reset = (mp > thr) ? 1.0 : 0.0;
            double mem = beta * mp + cur - reset * thr;
            cfp[j]=(float)cur; mfp[j]=(float)mem; sfp[j]=(mem > thr)?1.f:0.f;
            if (m64_out) m64_out[off + j] = mem;
        }
        *reinterpret_cast<float4*>(cur_out + off) = cf;
        *reinterpret_cast<float4*>(mem_out + off) = mf;
        *reinterpret_cast<float4*>(spk_out + off) = sf;
    }
}

extern "C" void kernel_launch(void* const* d_in, const int* in_sizes, int n_in,
                              void* d_out, int out_size, void* d_ws, size_t ws_size,
                              hipStream_t stream) {
    const float* x  = (const float*)d_in[0];
    const float* W1 = (const float*)d_in[1];  const float* b1 = (const float*)d_in[2];
    const float* W2 = (const float*)d_in[3];  const float* b2 = (const float*)d_in[4];
    const float* W3 = (const float*)d_in[5];  const float* b3 = (const float*)d_in[6];
    const float* W4 = (const float*)d_in[7];  const float* b4 = (const float*)d_in[8];
    const float* beta1 = (const float*)d_in[9];  const float* beta2 = (const float*)d_in[10];
    const float* beta3 = (const float*)d_in[11]; const float* beta4 = (const float*)d_in[12];
    const float* thr1 = (const float*)d_in[13];  const float* thr2 = (const float*)d_in[14];
    const float* thr3 = (const float*)d_in[15];  const float* thr4 = (const float*)d_in[16];

    float* out = (float*)d_out;
    const size_t SB = (size_t)T_ * PT, SB4 = (size_t)T_ * PT4;
    float* s1 = out;            float* s2 = out + SB;   float* s3 = out + 2*SB; float* s4 = out + 3*SB;
    float* m1 = s4 + SB4;       float* m2 = m1 + SB;    float* m3 = m1 + 2*SB;  float* m4 = m1 + 3*SB;
    float* c1 = m4 + SB4;       float* c2 = c1 + SB;    float* c3 = c1 + 2*SB;  float* c4 = c1 + 3*SB;

    // workspace layout (i8 path)
    const size_t XPL = 5ull*6400*768, W1PL = 5ull*768*2048, W23PL = 4ull*2048*2048;
    const size_t S1Q = (size_t)T_*PT, S2Q = PT;
    const size_t M2B = (size_t)PT*8, M4B = (size_t)PT4*8;
    size_t need = XPL + W1PL + 2*W23PL + S1Q + S2Q + 2*M2B + M4B;

    if (ws_size >= need) {
        char* w = (char*)d_ws;
        char* xpl  = w;              char* w1pl = xpl + XPL;
        char* w2pl = w1pl + W1PL;    char* w3pl = w2pl + W23PL;
        char* s1q  = w3pl + W23PL;   char* s2q  = s1q + S1Q;
        double* m2ws = (double*)(s2q + S2Q);
        double* m3ws = (double*)((char*)m2ws + M2B);
        double* m4ws = (double*)((char*)m3ws + M2B);

        k_decomp_x<<<1200, 256, 0, stream>>>(x, xpl);
        k_decomp_w<5,42,24><<<384, 256, 0, stream>>>(W1, w1pl, 768);
        k_decomp_w<4,35,64><<<1024, 256, 0, stream>>>(W2, w2pl, 2048);
        k_decomp_w<4,35,64><<<1024, 256, 0, stream>>>(W3, w3pl, 2048);
        k_gemm1<<<dim3(64, 50), 256, 0, stream>>>(xpl, w1pl, b1, c1);
        k_lif1<<<2048, 256, 0, stream>>>(c1, m1, s1, s1q, beta1, thr1);

        for (int t = 0; t < T_; ++t) {
            size_t po = (size_t)t * PT, po4 = (size_t)t * PT4;
            k_gemm23<<<dim3(64, 8), 64, 0, stream>>>(
                s1q + po, w2pl, b2, m2ws, c2 + po, m2 + po, s2 + po, s2q, beta2, thr2, t == 0);
            k_gemm23<<<dim3(64, 8), 64, 0, stream>>>(
                s2q, w3pl, b3, m3ws, c3 + po, m3 + po, s3 + po, nullptr, beta3, thr3, t == 0);
            k_fc4<<<64, 256, 0, stream>>>(
                s3 + po, W4, b4, m4ws, c4 + po4, m4 + po4, s4 + po4, beta4, thr4, t == 0);
        }
        return;
    }

    // -------- fp64 fallback (round-2 verified) --------
    const size_t NL = PT;
    const size_t WS_NEED = (3 * NL + PT4) * sizeof(double);
    const bool use64 = (d_ws != nullptr) && (ws_size >= WS_NEED);
    double* wsd = (double*)d_ws;
    double* mm1 = use64 ? wsd : nullptr;
    double* mm2 = use64 ? wsd + NL : nullptr;
    double* mm3 = use64 ? wsd + 2 * NL : nullptr;
    double* mm4 = use64 ? wsd + 3 * NL : nullptr;
    const dim3 grid(HH / BN, BB / BM);
    for (int t = 0; t < T_; ++t) {
        size_t po = (size_t)t * PT, po4 = (size_t)t * PT4;
        gemm_lif_f64<<<grid, 256, 0, stream>>>(x + (size_t)t * DIN, T_ * DIN, W1, b1,
            t ? mm1 : nullptr, t ? m1 + po - PT : nullptr, mm1,
            c1 + po, m1 + po, s1 + po, beta1, thr1, DIN, HH);
        gemm_lif_f64<<<grid, 256, 0, stream>>>(s1 + po, HH, W2, b2,
            t ? mm2 : nullptr, t ? m2 + po - PT : nullptr, mm2,
            c2 + po, m2 + po, s2 + po, beta2, thr2, HH, HH);
        gemm_lif_f64<<<grid, 256, 0, stream>>>(s2 + po, HH, W3, b3,
            t ? mm3 : nullptr, t ? m3 + po - PT : nullptr, mm3,
            c3 + po, m3 + po, s3 + po, beta3, thr3, HH, HH);
        k_fc4<<<64, 256, 0, stream>>>(s3 + po, W4, b4,
            mm4 ? mm4 : (double*)d_ws, c4 + po4, m4 + po4, s4 + po4, beta4, thr4, t == 0);
    }
}

// Round 4
// 733.268 us; speedup vs baseline: 12.0740x; 3.2729x over previous
//
#include <hip/hip_runtime.h>

// SNN 4-layer LIF, T=25, B=256 — batched-time formulation.
// All GEMMs computed for all 25 timesteps at once (M=6400); the only
// sequential part is the elementwise membrane scan per layer.
// GEMM arithmetic exact (i8 digit planes, i32 MFMA accum, fp64 reconstruct);
// LIF recursion fp64 in registers; cur passed between kernels as f32+f32
// residual (res stored in the m-region of d_out before the scan overwrites it).

typedef int v4i  __attribute__((ext_vector_type(4)));
typedef int v16i __attribute__((ext_vector_type(16)));

#define T_   25
#define BB   256
#define DIN  768
#define HH   2048
#define PT   (BB*HH)
#define PT4  (BB*10)

// ---------------- digit decompose (validated round 3) ----------------
// x[B][T][DIN] -> 5 planes, scale 2^35, A-fragment swizzled:
// [rtile(200)][kc(24)][plane(5)][lane(64)][16B], row r = t*256+b
__global__ __launch_bounds__(256)
void k_decomp_x(const float* __restrict__ x, char* __restrict__ xpl)
{
    int gid = blockIdx.x * 256 + threadIdx.x;      // 6400*48
    int r = gid / 48, rem = gid % 48;
    int kc = rem >> 1, h = rem & 1;
    int t = r >> 8, b = r & 255;
    const float* src = x + ((size_t)b * T_ + t) * DIN + kc * 32 + h * 16;
    alignas(16) char dig[5][16];
#pragma unroll
    for (int e = 0; e < 16; ++e) {
        long long V = llround((double)src[e] * 34359738368.0);  // 2^35
#pragma unroll
        for (int p = 0; p < 4; ++p) {
            int d = (int)(V & 255); if (d >= 128) d -= 256;
            dig[p][e] = (char)d; V = (V - d) >> 8;
        }
        dig[4][e] = (char)V;
    }
    size_t base = (((size_t)(r >> 5) * 24 + kc) * 5) * 1024 + (size_t)(h * 32 + (r & 31)) * 16;
#pragma unroll
    for (int p = 0; p < 5; ++p)
        *(int4*)(xpl + base + (size_t)p * 1024) = *(const int4*)dig[p];
}

// W[N=2048][K] -> NDIG planes, scale 2^QSH, B-fragment swizzled
template<int NDIG, int QSH, int KC>
__global__ __launch_bounds__(256)
void k_decomp_w(const float* __restrict__ W, char* __restrict__ wpl, int K)
{
    int gid = blockIdx.x * 256 + threadIdx.x;      // 2048*KC*2
    int n = gid / (KC * 2), rem = gid % (KC * 2);
    int kc = rem >> 1, h = rem & 1;
    const float* src = W + (size_t)n * K + kc * 32 + h * 16;
    const double scale = (double)(1ULL << QSH);
    alignas(16) char dig[NDIG][16];
#pragma unroll
    for (int e = 0; e < 16; ++e) {
        long long V = llround((double)src[e] * scale);
#pragma unroll
        for (int p = 0; p < NDIG - 1; ++p) {
            int d = (int)(V & 255); if (d >= 128) d -= 256;
            dig[p][e] = (char)d; V = (V - d) >> 8;
        }
        dig[NDIG - 1][e] = (char)V;
    }
    size_t base = (((size_t)(n >> 5) * KC + kc) * NDIG) * 1024 + (size_t)(h * 32 + (n & 31)) * 16;
#pragma unroll
    for (int p = 0; p < NDIG; ++p)
        *(int4*)(wpl + base + (size_t)p * 1024) = *(const int4*)dig[p];
}

// ---------------- GEMM1: c1[6400][2048] = x @ W1^T + b1 (exact) ----------------
__global__ __launch_bounds__(256)
void k_gemm1(const char* __restrict__ xpl, const char* __restrict__ w1pl,
             const float* __restrict__ b1, float* __restrict__ c_out,
             float* __restrict__ res_out)
{
    int wid = threadIdx.x >> 6, l = threadIdx.x & 63;
    int mt = blockIdx.y * 4 + wid;     // 0..199
    int nt = blockIdx.x;               // 0..63
    v16i acc[5] = {};
    const char* ab = xpl  + ((size_t)mt * 24) * 5 * 1024 + (size_t)l * 16;
    const char* wb = w1pl + ((size_t)nt * 24) * 5 * 1024 + (size_t)l * 16;
    for (int kc = 0; kc < 24; ++kc) {
        v4i a[5], w[5];
#pragma unroll
        for (int p = 0; p < 5; ++p) {
            a[p] = *(const v4i*)(ab + (size_t)(kc * 5 + p) * 1024);
            w[p] = *(const v4i*)(wb + (size_t)(kc * 5 + p) * 1024);
        }
        acc[0] = __builtin_amdgcn_mfma_i32_32x32x32_i8(a[0], w[4], acc[0], 0, 0, 0);
        acc[0] = __builtin_amdgcn_mfma_i32_32x32x32_i8(a[1], w[3], acc[0], 0, 0, 0);
        acc[0] = __builtin_amdgcn_mfma_i32_32x32x32_i8(a[2], w[2], acc[0], 0, 0, 0);
        acc[0] = __builtin_amdgcn_mfma_i32_32x32x32_i8(a[3], w[1], acc[0], 0, 0, 0);
        acc[0] = __builtin_amdgcn_mfma_i32_32x32x32_i8(a[4], w[0], acc[0], 0, 0, 0);
        acc[1] = __builtin_amdgcn_mfma_i32_32x32x32_i8(a[1], w[4], acc[1], 0, 0, 0);
        acc[1] = __builtin_amdgcn_mfma_i32_32x32x32_i8(a[2], w[3], acc[1], 0, 0, 0);
        acc[1] = __builtin_amdgcn_mfma_i32_32x32x32_i8(a[3], w[2], acc[1], 0, 0, 0);
        acc[1] = __builtin_amdgcn_mfma_i32_32x32x32_i8(a[4], w[1], acc[1], 0, 0, 0);
        acc[2] = __builtin_amdgcn_mfma_i32_32x32x32_i8(a[2], w[4], acc[2], 0, 0, 0);
        acc[2] = __builtin_amdgcn_mfma_i32_32x32x32_i8(a[3], w[3], acc[2], 0, 0, 0);
        acc[2] = __builtin_amdgcn_mfma_i32_32x32x32_i8(a[4], w[2], acc[2], 0, 0, 0);
        acc[3] = __builtin_amdgcn_mfma_i32_32x32x32_i8(a[3], w[4], acc[3], 0, 0, 0);
        acc[3] = __builtin_amdgcn_mfma_i32_32x32x32_i8(a[4], w[3], acc[3], 0, 0, 0);
        acc[4] = __builtin_amdgcn_mfma_i32_32x32x32_i8(a[4], w[4], acc[4], 0, 0, 0);
    }
    int half = l >> 5, lr = l & 31;
    int col = nt * 32 + lr;
    double bias = (double)b1[col];
#pragma unroll
    for (int e = 0; e < 16; ++e) {
        int row = (e & 3) + 8 * (e >> 2) + 4 * half;
        int r = mt * 32 + row;
        double hi = (((double)acc[4][e] * 256.0 + (double)acc[3][e]) * 256.0 + (double)acc[2][e]);
        double lo = ((double)acc[1][e] * 256.0 + (double)acc[0][e]);
        double v = hi * 1.862645149230957e-09 + lo * 2.842170943040401e-14 + bias;
        float cf = (float)v;
        float rf = (float)(v - (double)cf);
        size_t off = (size_t)r * HH + col;
        c_out[off] = cf; res_out[off] = rf;
    }
}

// ---------------- GEMM2/3: c[6400][2048] = spikes(i8) @ W(4 planes)^T + b ----------------
// A pre-swizzled: [rtile(200)][kc(64)][lane(64)][16B]
__global__ __launch_bounds__(256)
void k_gemm23(const char* __restrict__ aq, const char* __restrict__ wpl,
              const float* __restrict__ bias,
              float* __restrict__ c_out, float* __restrict__ res_out)
{
    int wid = threadIdx.x >> 6, l = threadIdx.x & 63;
    int half = l >> 5, lr = l & 31;
    int nt = blockIdx.x, mt = blockIdx.y * 4 + wid;   // 0..63, 0..199
    v16i acc[4] = {};
    const char* ab = aq + (size_t)mt * 65536 + (size_t)l * 16;
    const char* wb = wpl + ((size_t)nt * 64) * 4 * 1024 + (size_t)l * 16;
#pragma unroll 4
    for (int kc = 0; kc < 64; ++kc) {
        v4i a  = *(const v4i*)(ab + (size_t)kc * 1024);
        v4i w0 = *(const v4i*)(wb + (size_t)(kc * 4 + 0) * 1024);
        v4i w1 = *(const v4i*)(wb + (size_t)(kc * 4 + 1) * 1024);
        v4i w2 = *(const v4i*)(wb + (size_t)(kc * 4 + 2) * 1024);
        v4i w3 = *(const v4i*)(wb + (size_t)(kc * 4 + 3) * 1024);
        acc[0] = __builtin_amdgcn_mfma_i32_32x32x32_i8(a, w0, acc[0], 0, 0, 0);
        acc[1] = __builtin_amdgcn_mfma_i32_32x32x32_i8(a, w1, acc[1], 0, 0, 0);
        acc[2] = __builtin_amdgcn_mfma_i32_32x32x32_i8(a, w2, acc[2], 0, 0, 0);
        acc[3] = __builtin_amdgcn_mfma_i32_32x32x32_i8(a, w3, acc[3], 0, 0, 0);
    }
    int col = nt * 32 + lr;
    double bv = (double)bias[col];
#pragma unroll
    for (int e = 0; e < 16; ++e) {
        int row = (e & 3) + 8 * (e >> 2) + 4 * half;
        size_t off = (size_t)(mt * 32 + row) * HH + col;
        double dot = ((((double)acc[3][e] * 256.0 + (double)acc[2][e]) * 256.0
                       + (double)acc[1][e]) * 256.0 + (double)acc[0][e]) * 2.9103830456733704e-11; // 2^-35
        double v = dot + bv;
        float cf = (float)v;
        float rf = (float)(v - (double)cf);
        c_out[off] = cf; res_out[off] = rf;
    }
}

// ---------------- LIF scan (elementwise over t), fp64 state in registers ----------------
// res_m: residual in, m out (same buffer, per-thread exclusive addresses).
// SWZ: also emit spikes as i8 in MFMA-A-swizzled plane for the next GEMM.
template<bool SWZ>
__global__ __launch_bounds__(256)
void k_scan(const float* __restrict__ c, float* __restrict__ res_m,
            float* __restrict__ s, char* __restrict__ sq,
            const float* __restrict__ beta_p, const float* __restrict__ thr_p)
{
    int idx = blockIdx.x * 256 + threadIdx.x;   // 65536 threads, 8 elems each
    int b = idx >> 8, n0 = (idx & 255) << 3;
    double beta = fmin(fmax((double)*beta_p, 0.0), 1.0);
    double thr  = (double)*thr_p;
    double mem[8];
#pragma unroll
    for (int e = 0; e < 8; ++e) mem[e] = 0.0;
    const size_t base = (size_t)b * HH + n0;
    const int kc = n0 >> 5, halfk = (n0 >> 4) & 1, b8 = n0 & 8;

    for (int t = 0; t < T_; ++t) {
        size_t off = (size_t)t * PT + base;
        float4 cv0 = *(const float4*)(c + off);
        float4 cv1 = *(const float4*)(c + off + 4);
        float4 rv0 = *(const float4*)(res_m + off);
        float4 rv1 = *(const float4*)(res_m + off + 4);
        float cf[8] = {cv0.x,cv0.y,cv0.z,cv0.w,cv1.x,cv1.y,cv1.z,cv1.w};
        float rf[8] = {rv0.x,rv0.y,rv0.z,rv0.w,rv1.x,rv1.y,rv1.z,rv1.w};
        float mf[8], sf[8];
        alignas(8) char sb[8];
#pragma unroll
        for (int e = 0; e < 8; ++e) {
            double cur = (double)cf[e] + (double)rf[e];
            double reset = (mem[e] > thr) ? 1.0 : 0.0;
            mem[e] = beta * mem[e] + cur - reset * thr;
            bool sp = mem[e] > thr;
            mf[e] = (float)mem[e]; sf[e] = sp ? 1.f : 0.f; sb[e] = sp ? 1 : 0;
        }
        *(float4*)(res_m + off)     = *(float4*)(mf);
        *(float4*)(res_m + off + 4) = *(float4*)(mf + 4);
        *(float4*)(s + off)         = *(float4*)(sf);
        *(float4*)(s + off + 4)     = *(float4*)(sf + 4);
        if (SWZ) {
            int r = t * 256 + b;
            size_t sa = ((size_t)((r >> 5) * 64 + kc)) * 1024
                      + (size_t)(halfk * 32 + (r & 31)) * 16 + b8;
            *(int2*)(sq + sa) = *(const int2*)sb;
        }
    }
}

// ---------------- GEMM4: c4[6400][10] = s3 @ W4^T + b4 (fp64 wave-dot) ----------------
__global__ __launch_bounds__(256)
void k_gemm4(const float* __restrict__ A, const float* __restrict__ W,
             const float* __restrict__ bias,
             float* __restrict__ c_out, float* __restrict__ res_out)
{
    int wid = threadIdx.x >> 6, lane = threadIdx.x & 63;
    int i = blockIdx.x * 4 + wid;     // 0..6399
    double a[32];
#pragma unroll
    for (int m = 0; m < 32; ++m)
        a[m] = (double)A[(size_t)i * HH + lane + 64 * m];
    for (int j = 0; j < 10; ++j) {
        double s = 0.0;
#pragma unroll
        for (int m = 0; m < 32; ++m)
            s += a[m] * (double)W[(size_t)j * HH + lane + 64 * m];
#pragma unroll
        for (int o = 32; o > 0; o >>= 1)
            s += __shfl_down(s, o);
        if (lane == 0) {
            double v = s + (double)bias[j];
            float cf = (float)v;
            float rf = (float)(v - (double)cf);
            c_out[i * 10 + j] = cf; res_out[i * 10 + j] = rf;
        }
    }
}

__global__ __launch_bounds__(256)
void k_scan4(const float* __restrict__ c, float* __restrict__ res_m,
             float* __restrict__ s,
             const float* __restrict__ beta_p, const float* __restrict__ thr_p)
{
    int idx = blockIdx.x * 256 + threadIdx.x;
    if (idx >= PT4) return;
    double beta = fmin(fmax((double)*beta_p, 0.0), 1.0);
    double thr  = (double)*thr_p;
    double mem = 0.0;
    for (int t = 0; t < T_; ++t) {
        size_t off = (size_t)t * PT4 + idx;
        double cur = (double)c[off] + (double)res_m[off];
        double reset = (mem > thr) ? 1.0 : 0.0;
        mem = beta * mem + cur - reset * thr;
        res_m[off] = (float)mem;
        s[off] = (mem > thr) ? 1.f : 0.f;
    }
}

// ---------------- fp64 fallback (round-2 verified) ----------------
#define BM 32
#define BN 64
#define BK 32
__global__ __launch_bounds__(256)
void gemm_lif_f64(const float* __restrict__ A, int lda, const float* __restrict__ W,
                  const float* __restrict__ bias, const double* __restrict__ m64_in,
                  const float* __restrict__ m32_in, double* __restrict__ m64_out,
                  float* __restrict__ cur_out, float* __restrict__ mem_out, float* __restrict__ spk_out,
                  const float* __restrict__ beta_p, const float* __restrict__ thr_p, int K, int N)
{
    __shared__ double As[BK][BM + 4];
    __shared__ double Ws[BK][BN + 4];
    const int tid = threadIdx.x;
    const int bm = blockIdx.y * BM, bn = blockIdx.x * BN;
    const int tx = tid & 15, ty = tid >> 4;
    const int n0 = tx * 4, m0 = ty * 2;
    const int arow = tid >> 3, acol = (tid & 7) * 4;
    double acc[2][4] = {{0,0,0,0},{0,0,0,0}};
    for (int kt = 0; kt < K; kt += BK) {
        float4 av = *reinterpret_cast<const float4*>(A + (size_t)(bm + arow) * lda + kt + acol);
        As[acol+0][arow]=av.x; As[acol+1][arow]=av.y; As[acol+2][arow]=av.z; As[acol+3][arow]=av.w;
#pragma unroll
        for (int r = 0; r < 2; ++r) {
            int n = arow + r * 32;
            float4 wv = *reinterpret_cast<const float4*>(W + (size_t)(bn + n) * K + kt + acol);
            Ws[acol+0][n]=wv.x; Ws[acol+1][n]=wv.y; Ws[acol+2][n]=wv.z; Ws[acol+3][n]=wv.w;
        }
        __syncthreads();
#pragma unroll
        for (int k = 0; k < BK; ++k) {
            double2 a  = *reinterpret_cast<const double2*>(&As[k][m0]);
            double2 w0 = *reinterpret_cast<const double2*>(&Ws[k][n0]);
            double2 w1 = *reinterpret_cast<const double2*>(&Ws[k][n0 + 2]);
            acc[0][0]+=a.x*w0.x; acc[0][1]+=a.x*w0.y; acc[0][2]+=a.x*w1.x; acc[0][3]+=a.x*w1.y;
            acc[1][0]+=a.y*w0.x; acc[1][1]+=a.y*w0.y; acc[1][2]+=a.y*w1.x; acc[1][3]+=a.y*w1.y;
        }
        __syncthreads();
    }
    const double beta = fmin(fmax((double)*beta_p, 0.0), 1.0);
    const double thr  = (double)*thr_p;
#pragma unroll
    for (int r = 0; r < 2; ++r) {
        const size_t off = (size_t)(bm + m0 + r) * N + bn + n0;
        float4 cf, mf, sf;
        float* cfp=&cf.x; float* mfp=&mf.x; float* sfp=&sf.x;
#pragma unroll
        for (int j = 0; j < 4; ++j) {
            double cur = acc[r][j] + (double)bias[bn + n0 + j];
            double mp = m64_in ? m64_in[off + j] : (m32_in ? (double)m32_in[off + j] : 0.0);
            double reset = (mp > thr) ? 1.0 : 0.0;
            double mem = beta * mp + cur - reset * thr;
            cfp[j]=(float)cur; mfp[j]=(float)mem; sfp[j]=(mem > thr)?1.f:0.f;
            if (m64_out) m64_out[off + j] = mem;
        }
        *reinterpret_cast<float4*>(cur_out + off) = cf;
        *reinterpret_cast<float4*>(mem_out + off) = mf;
        *reinterpret_cast<float4*>(spk_out + off) = sf;
    }
}

__global__ __launch_bounds__(256)
void k_fc4_lif(const float* __restrict__ A, const float* __restrict__ W,
               const float* __restrict__ bias, double* __restrict__ m4ws,
               float* __restrict__ c4, float* __restrict__ m4, float* __restrict__ s4,
               const float* __restrict__ beta_p, const float* __restrict__ thr_p, int t0)
{
    int wid = threadIdx.x >> 6, lane = threadIdx.x & 63;
    int i = blockIdx.x * 4 + wid;
    double a[32];
#pragma unroll
    for (int m = 0; m < 32; ++m)
        a[m] = (double)A[(size_t)i * HH + lane + 64 * m];
    double beta = fmin(fmax((double)*beta_p, 0.0), 1.0);
    double thr  = (double)*thr_p;
    for (int j = 0; j < 10; ++j) {
        double s = 0.0;
#pragma unroll
        for (int m = 0; m < 32; ++m)
            s += a[m] * (double)W[(size_t)j * HH + lane + 64 * m];
#pragma unroll
        for (int o = 32; o > 0; o >>= 1)
            s += __shfl_down(s, o);
        if (lane == 0) {
            double cur = s + (double)bias[j];
            double mp = t0 ? 0.0 : m4ws[i * 10 + j];
            double reset = (mp > thr) ? 1.0 : 0.0;
            double mem = beta * mp + cur - reset * thr;
            c4[i * 10 + j] = (float)cur; m4[i * 10 + j] = (float)mem;
            s4[i * 10 + j] = (mem > thr) ? 1.f : 0.f;
            m4ws[i * 10 + j] = mem;
        }
    }
}

extern "C" void kernel_launch(void* const* d_in, const int* in_sizes, int n_in,
                              void* d_out, int out_size, void* d_ws, size_t ws_size,
                              hipStream_t stream) {
    const float* x  = (const float*)d_in[0];
    const float* W1 = (const float*)d_in[1];  const float* b1 = (const float*)d_in[2];
    const float* W2 = (const float*)d_in[3];  const float* b2 = (const float*)d_in[4];
    const float* W3 = (const float*)d_in[5];  const float* b3 = (const float*)d_in[6];
    const float* W4 = (const float*)d_in[7];  const float* b4 = (const float*)d_in[8];
    const float* beta1 = (const float*)d_in[9];  const float* beta2 = (const float*)d_in[10];
    const float* beta3 = (const float*)d_in[11]; const float* beta4 = (const float*)d_in[12];
    const float* thr1 = (const float*)d_in[13];  const float* thr2 = (const float*)d_in[14];
    const float* thr3 = (const float*)d_in[15];  const float* thr4 = (const float*)d_in[16];

    float* out = (float*)d_out;
    const size_t SB = (size_t)T_ * PT, SB4 = (size_t)T_ * PT4;
    float* s1 = out;            float* s2 = out + SB;   float* s3 = out + 2*SB; float* s4 = out + 3*SB;
    float* m1 = s4 + SB4;       float* m2 = m1 + SB;    float* m3 = m1 + 2*SB;  float* m4 = m1 + 3*SB;
    float* c1 = m4 + SB4;       float* c2 = c1 + SB;    float* c3 = c1 + 2*SB;  float* c4 = c1 + 3*SB;

    // workspace: digit planes + swizzled spike planes
    const size_t XPL = 5ull*6400*768, W1PL = 5ull*2048*768, W23PL = 4ull*2048*2048;
    const size_t SQ = 6400ull*2048;
    size_t need = XPL + W1PL + 2*W23PL + 2*SQ;   // ~92.2 MB

    if (ws_size >= need) {
        char* w = (char*)d_ws;
        char* xpl  = w;              char* w1pl = xpl + XPL;
        char* w2pl = w1pl + W1PL;    char* w3pl = w2pl + W23PL;
        char* s1q  = w3pl + W23PL;   char* s2q  = s1q + SQ;

        k_decomp_x<<<1200, 256, 0, stream>>>(x, xpl);
        k_decomp_w<5,42,24><<<384, 256, 0, stream>>>(W1, w1pl, 768);
        k_decomp_w<4,35,64><<<1024, 256, 0, stream>>>(W2, w2pl, 2048);
        k_decomp_w<4,35,64><<<1024, 256, 0, stream>>>(W3, w3pl, 2048);

        k_gemm1<<<dim3(64, 50), 256, 0, stream>>>(xpl, w1pl, b1, c1, m1);
        k_scan<true><<<256, 256, 0, stream>>>(c1, m1, s1, s1q, beta1, thr1);
        k_gemm23<<<dim3(64, 50), 256, 0, stream>>>(s1q, w2pl, b2, c2, m2);
        k_scan<true><<<256, 256, 0, stream>>>(c2, m2, s2, s2q, beta2, thr2);
        k_gemm23<<<dim3(64, 50), 256, 0, stream>>>(s2q, w3pl, b3, c3, m3);
        k_scan<false><<<256, 256, 0, stream>>>(c3, m3, s3, nullptr, beta3, thr3);
        k_gemm4<<<1600, 256, 0, stream>>>(s3, W4, b4, c4, m4);
        k_scan4<<<10, 256, 0, stream>>>(c4, m4, s4, beta4, thr4);
        return;
    }

    // -------- fp64 fallback (round-2 verified) --------
    const size_t NL = PT;
    const size_t WS_NEED = (3 * NL + PT4) * sizeof(double);
    const bool use64 = (d_ws != nullptr) && (ws_size >= WS_NEED);
    double* wsd = (double*)d_ws;
    double* mm1 = use64 ? wsd : nullptr;
    double* mm2 = use64 ? wsd + NL : nullptr;
    double* mm3 = use64 ? wsd + 2 * NL : nullptr;
    double* mm4 = use64 ? wsd + 3 * NL : nullptr;
    const dim3 grid(HH / BN, BB / BM);
    for (int t = 0; t < T_; ++t) {
        size_t po = (size_t)t * PT, po4 = (size_t)t * PT4;
        gemm_lif_f64<<<grid, 256, 0, stream>>>(x + (size_t)t * DIN, T_ * DIN, W1, b1,
            t ? mm1 : nullptr, t ? m1 + po - PT : nullptr, mm1,
            c1 + po, m1 + po, s1 + po, beta1, thr1, DIN, HH);
        gemm_lif_f64<<<grid, 256, 0, stream>>>(s1 + po, HH, W2, b2,
            t ? mm2 : nullptr, t ? m2 + po - PT : nullptr, mm2,
            c2 + po, m2 + po, s2 + po, beta2, thr2, HH, HH);
        gemm_lif_f64<<<grid, 256, 0, stream>>>(s2 + po, HH, W3, b3,
            t ? mm3 : nullptr, t ? m3 + po - PT : nullptr, mm3,
            c3 + po, m3 + po, s3 + po, beta3, thr3, HH, HH);
        k_fc4_lif<<<64, 256, 0, stream>>>(s3 + po, W4, b4,
            mm4 ? mm4 : (double*)d_ws, c4 + po4, m4 + po4, s4 + po4, beta4, thr4, t == 0);
    }
}